// Round 1
// baseline (247.265 us; speedup 1.0000x reference)
//
#include <hip/hip_runtime.h>

// WaveletMixing: out = x + IDWT3(scale(DWT3(x)))  along N, per (b,d) channel.
// x: (B=8, N=4096, D=768) f32, w_approx: (D,), w_details: (3, D).
// One block per (b,d) row; full pipeline in LDS (~44 KB -> 3 blocks/CU).
// Rows are strided by D floats in global memory; XCD-aware block swizzle makes
// the 16 consecutive-d blocks sharing each 64B line run on one XCD (L2 merge).

namespace {

constexpr int NT  = 256;                 // threads per block
constexpr int N0  = 4096;                // signal length
constexpr int L1  = (N0 + 7) / 2;        // 2051  (symmetric-mode dwt length)
constexpr int L2  = (L1 + 7) / 2;        // 1029
constexpr int L3  = (L2 + 7) / 2;        // 518
constexpr int DCH = 768;                 // channels

// db4 analysis filters, ascending order (pywt). HI[k] = (-1)^(k+1) * LO[7-k].
constexpr float LO[8] = {
  -0.010597401784997278f,  0.032883011666982945f,  0.030841381835986965f,
  -0.18703481171888114f,  -0.02798376941698385f,   0.6308807679295904f,
   0.7148465705525415f,    0.23037781330885523f };
constexpr float HI[8] = {
  -0.23037781330885523f,   0.7148465705525415f,   -0.6308807679295904f,
  -0.02798376941698385f,   0.18703481171888114f,   0.030841381835986965f,
  -0.032883011666982945f, -0.010597401784997278f };

// One symmetric-mode analysis level: y_{lo,hi}[i] = sum_j F[j]*in_sym(2i+1-j).
// Reflection is single-bounce for all our sizes (pad 6/7 << n).
__device__ __forceinline__ void dwt_phase(const float* __restrict__ in, int n,
                                          float* __restrict__ ca,
                                          float* __restrict__ cd,
                                          int L, int tid) {
  for (int i = tid; i < L; i += NT) {
    const int base = 2 * i + 1;
    float alo = 0.f, ahi = 0.f;
#pragma unroll
    for (int j = 0; j < 8; ++j) {
      int t = base - j;                    // in [2i-6, 2i+1]
      t = (t < 0) ? (-t - 1) : t;          // left symmetric reflect
      t = (t >= n) ? (2 * n - 1 - t) : t;  // right symmetric reflect
      const float v = in[t];
      alo = fmaf(LO[j], v, alo);
      ahi = fmaf(HI[j], v, ahi);
    }
    ca[i] = alo;
    cd[i] = ahi;
  }
}

} // namespace

__global__ __launch_bounds__(NT) void wavemix_kernel(
    const float* __restrict__ x, const float* __restrict__ w_approx,
    const float* __restrict__ w_details, float* __restrict__ out) {
  __shared__ float sig[N0];
  __shared__ float a1[L1], d1[L1];   // a1 later reused as r1
  __shared__ float a2[L2], d2[L2];   // a2 later reused as r2
  __shared__ float a3[L3], d3[L3];

  // Bijective XCD swizzle: grid = B*DCH (6144, % 8 == 0). XCD x gets a
  // contiguous run of (b,d) rows -> consecutive-d blocks co-resident per XCD.
  const int nwg = gridDim.x;
  const int cpx = nwg >> 3;
  const int wg  = (blockIdx.x & 7) * cpx + (blockIdx.x >> 3);
  const int b   = wg / DCH;
  const int d   = wg - b * DCH;
  const int tid = threadIdx.x;

  const float* __restrict__ xrow = x   + (size_t)b * N0 * DCH + d;
  float* __restrict__       orow = out + (size_t)b * N0 * DCH + d;

  // ---- load row (stride DCH floats; L2 merges across neighboring-d blocks)
  for (int n = tid; n < N0; n += NT) sig[n] = xrow[(size_t)n * DCH];

  // per-channel weights (uniform across block -> broadcast loads)
  const float wa  = w_approx[d];
  const float wd0 = w_details[0 * DCH + d];   // level-1 detail weight
  const float wd1 = w_details[1 * DCH + d];   // level-2
  const float wd2 = w_details[2 * DCH + d];   // level-3
  __syncthreads();

  // ---- analysis
  dwt_phase(sig, N0, a1, d1, L1, tid);
  __syncthreads();
  dwt_phase(a1, L1, a2, d2, L2, tid);
  __syncthreads();
  dwt_phase(a2, L2, a3, d3, L3, tid);
  __syncthreads();

  // ---- synthesis level 3: r2 = idwt(wa*a3, wd2*d3), len L2, into a2.
  // rec[2t]   = sum_m LO[2m+1]*ca[t+m] + HI[2m+1]*cd[t+m]
  // rec[2t+1] = sum_m LO[2m  ]*ca[t+m] + HI[2m  ]*cd[t+m]
  // For our sizes t+3 < Lc always holds (no zero-pad checks needed).
  for (int t = tid; 2 * t < L2; t += NT) {
    float eca = 0.f, ecd = 0.f, oca = 0.f, ocd = 0.f;
#pragma unroll
    for (int m = 0; m < 4; ++m) {
      const float a  = a3[t + m];
      const float dd = d3[t + m];
      eca = fmaf(LO[2 * m + 1], a,  eca);
      ecd = fmaf(HI[2 * m + 1], dd, ecd);
      oca = fmaf(LO[2 * m],     a,  oca);
      ocd = fmaf(HI[2 * m],     dd, ocd);
    }
    a2[2 * t] = wa * eca + wd2 * ecd;
    if (2 * t + 1 < L2) a2[2 * t + 1] = wa * oca + wd2 * ocd;
  }
  __syncthreads();

  // ---- synthesis level 2: r1 = idwt(r2, wd1*d2), len L1, into a1.
  for (int t = tid; 2 * t < L1; t += NT) {
    float eca = 0.f, ecd = 0.f, oca = 0.f, ocd = 0.f;
#pragma unroll
    for (int m = 0; m < 4; ++m) {
      const float a  = a2[t + m];
      const float dd = d2[t + m];
      eca = fmaf(LO[2 * m + 1], a,  eca);
      ecd = fmaf(HI[2 * m + 1], dd, ecd);
      oca = fmaf(LO[2 * m],     a,  oca);
      ocd = fmaf(HI[2 * m],     dd, ocd);
    }
    a1[2 * t] = eca + wd1 * ecd;
    if (2 * t + 1 < L1) a1[2 * t + 1] = oca + wd1 * ocd;
  }
  __syncthreads();

  // ---- synthesis level 1 + residual + store (N0 even: both outputs valid)
  for (int t = tid; 2 * t < N0; t += NT) {
    float eca = 0.f, ecd = 0.f, oca = 0.f, ocd = 0.f;
#pragma unroll
    for (int m = 0; m < 4; ++m) {
      const float a  = a1[t + m];
      const float dd = d1[t + m];
      eca = fmaf(LO[2 * m + 1], a,  eca);
      ecd = fmaf(HI[2 * m + 1], dd, ecd);
      oca = fmaf(LO[2 * m],     a,  oca);
      ocd = fmaf(HI[2 * m],     dd, ocd);
    }
    const int u = 2 * t;
    orow[(size_t)u * DCH]       = sig[u]     + (eca + wd0 * ecd);
    orow[(size_t)(u + 1) * DCH] = sig[u + 1] + (oca + wd0 * ocd);
  }
}

extern "C" void kernel_launch(void* const* d_in, const int* in_sizes, int n_in,
                              void* d_out, int out_size, void* d_ws, size_t ws_size,
                              hipStream_t stream) {
  const float* x  = (const float*)d_in[0];
  const float* wa = (const float*)d_in[1];
  const float* wd = (const float*)d_in[2];
  float* out      = (float*)d_out;

  const int B    = in_sizes[0] / (N0 * DCH);   // 8
  const int grid = B * DCH;                    // 6144, multiple of 8
  wavemix_kernel<<<grid, NT, 0, stream>>>(x, wa, wd, out);
}

// Round 2
// 126.355 us; speedup vs baseline: 1.9569x; 1.9569x over previous
//
#include <hip/hip_runtime.h>

// WaveletMixing: out = x + IDWT3(scale(DWT3(x))) along N per (b,d) channel.
// x: (B=8, N=4096, D=768) f32.
// Tiled: each block = 16 consecutive channels x 128 output samples (+ halo).
// All global accesses coalesced (lane = channel); full pipeline in LDS.

namespace {

constexpr int NT  = 256;
constexpr int N0  = 4096;
constexpr int L1v = 2051;           // symmetric-mode DWT lengths
constexpr int L2v = 1029;
constexpr int L3v = 518;
constexpr int DCH = 768;
constexpr int G   = 16;             // channels per block
constexpr int T   = 128;            // output samples per block
constexpr int NTI = N0 / T;         // 32 n-tiles
constexpr int NDG = DCH / G;        // 48 channel groups

// Exact dependence cone (db4, 3 levels):
//   out[n]  needs r1/d1[n/2 .. n/2+3]
//   r1[v]   needs r2/d2[v/2 .. v/2+3];  r2[u] needs a3/d3[u/2 .. u/2+3]
//   a1[i]   needs x[2i-6 .. 2i+1]  (and similarly down the chain)
// Extended (tile-relative) ranges:
constexpr int XLO  = -42;  constexpr int CX = T + 90;       // x:     [n0-42, n0+T+47]
constexpr int A1LO = -18;  constexpr int C1 = T / 2 + 42;   // a1/d1: [n0/2-18, (n0+T)/2+23]
constexpr int A2LO = -6;   constexpr int C2 = T / 4 + 18;   // a2/d2: [n0/4-6,  (n0+T)/4+11]
constexpr int C3 = T / 8 + 6;                               // a3/d3: [n0/8,    (n0+T)/8+5]
// Padded per-channel lengths, == 4 (mod 32): every LDS phase lands at
// exactly 2 lanes/bank (free on CDNA4).
constexpr int CXP = 228, C1P = 132, C2P = 68, C3P = 36;

// db4 analysis filters, ascending order (pywt). HI[k] = (-1)^(k+1)*LO[7-k].
__device__ constexpr float LO[8] = {
  -0.010597401784997278f,  0.032883011666982945f,  0.030841381835986965f,
  -0.18703481171888114f,  -0.02798376941698385f,   0.6308807679295904f,
   0.7148465705525415f,    0.23037781330885523f };
__device__ constexpr float HI[8] = {
  -0.23037781330885523f,   0.7148465705525415f,   -0.6308807679295904f,
  -0.02798376941698385f,   0.18703481171888114f,   0.030841381835986965f,
  -0.032883011666982945f, -0.010597401784997278f };

__device__ __forceinline__ int refl(int g, int n) {
  g = (g < 0) ? (-g - 1) : g;              // single-bounce symmetric reflect
  return (g >= n) ? (2 * n - 1 - g) : g;
}

// One analysis level over the tile's extended output range.
// in:  extended signal storage (values already symmetric-extended)
// out coeff p corresponds to global index loout_abs+p; reflected into
// [0,lenout) before computing, so stored values are themselves extended.
__device__ __forceinline__ void analyze(const float* __restrict__ in, int lpin,
                                        int loin_abs,
                                        float* __restrict__ oa,
                                        float* __restrict__ od, int lpout,
                                        int loout_abs, int nout, int lenout,
                                        int c, int i) {
  for (int p = i; p < nout; p += 16) {
    const int gp = refl(loout_abs + p, lenout);
    const int qb = 2 * gp + 1 - loin_abs;    // top tap, storage coords
    float alo = 0.f, ahi = 0.f;
#pragma unroll
    for (int j = 0; j < 8; ++j) {
      const float v = in[c * lpin + qb - j];
      alo = fmaf(LO[j], v, alo);
      ahi = fmaf(HI[j], v, ahi);
    }
    oa[c * lpout + p] = alo;
    od[c * lpout + p] = ahi;
  }
}

// One synthesis level: rec[2t] = sum_m LO[2m+1]*ca[t+m] + HI[2m+1]*cd[t+m],
// rec[2t+1] uses even taps; same 8 LDS reads serve both outputs.
__device__ __forceinline__ void synth(const float* __restrict__ ca,
                                      const float* __restrict__ cd, int lpin,
                                      int pcbase, float* __restrict__ o,
                                      int lpout, int pobase, float sa, float sd,
                                      int ntr, int c, int i) {
  for (int tr = i; tr < ntr; tr += 16) {
    float eca = 0.f, ecd = 0.f, oca = 0.f, ocd = 0.f;
#pragma unroll
    for (int m = 0; m < 4; ++m) {
      const float a = ca[c * lpin + pcbase + tr + m];
      const float d = cd[c * lpin + pcbase + tr + m];
      eca = fmaf(LO[2 * m + 1], a, eca);
      ecd = fmaf(HI[2 * m + 1], d, ecd);
      oca = fmaf(LO[2 * m],     a, oca);
      ocd = fmaf(HI[2 * m],     d, ocd);
    }
    o[c * lpout + pobase + 2 * tr]     = sa * eca + sd * ecd;
    o[c * lpout + pobase + 2 * tr + 1] = sa * oca + sd * ocd;
  }
}

} // namespace

__global__ __launch_bounds__(NT) void wavemix_kernel(
    const float* __restrict__ x, const float* __restrict__ wap,
    const float* __restrict__ wdet, float* __restrict__ out) {
  __shared__ float sx[G * CXP];
  __shared__ float sa1[G * C1P], sd1[G * C1P];  // sa1 later overwritten by r1
  __shared__ float sa2[G * C2P], sd2[G * C2P];  // sa2 later overwritten by r2
  __shared__ float sa3[G * C3P], sd3[G * C3P];

  // Bijective XCD swizzle; consecutive wg = consecutive n-tiles of one
  // (b, d-group) -> halo re-reads hit the same XCD's L2.
  const int cpx = gridDim.x >> 3;
  const int wg  = (blockIdx.x & 7) * cpx + (blockIdx.x >> 3);
  const int nt   = wg & (NTI - 1);
  const int rest = wg / NTI;
  const int dg   = rest % NDG;
  const int b    = rest / NDG;
  const int n0   = nt * T;
  const int d0   = dg * G;

  const int tid = threadIdx.x;
  const int c   = tid & (G - 1);     // channel lane (coalescing dim)
  const int i   = tid >> 4;          // 0..15 work slot

  const size_t rowbase = (size_t)b * N0 * DCH + d0 + c;

  // ---- load extended x tile (coalesced: 16 lanes = 64B line per row)
  for (int p = i; p < CX; p += 16) {
    const int g = refl(n0 + XLO + p, N0);
    sx[c * CXP + p] = x[rowbase + (size_t)g * DCH];
  }
  const float wa  = wap[d0 + c];
  const float wd0 = wdet[0 * DCH + d0 + c];
  const float wd1 = wdet[1 * DCH + d0 + c];
  const float wd2 = wdet[2 * DCH + d0 + c];
  __syncthreads();

  // ---- analysis
  analyze(sx,  CXP, n0 + XLO,      sa1, sd1, C1P, n0 / 2 + A1LO, C1, L1v, c, i);
  __syncthreads();
  analyze(sa1, C1P, n0 / 2 + A1LO, sa2, sd2, C2P, n0 / 4 + A2LO, C2, L2v, c, i);
  __syncthreads();
  analyze(sa2, C2P, n0 / 4 + A2LO, sa3, sd3, C3P, n0 / 8,        C3, L3v, c, i);
  __syncthreads();

  // ---- synthesis L3: r2 over [n0/4, (n0+T)/4+4] into sa2 (pos base 6)
  synth(sa3, sd3, C3P, 0, sa2, C2P, 6, wa, wd2, T / 8 + 3, c, i);
  __syncthreads();
  // ---- synthesis L2: r1 over [n0/2, (n0+T)/2+2] into sa1 (pos base 18)
  synth(sa2, sd2, C2P, 6, sa1, C1P, 18, 1.f, wd1, T / 4 + 2, c, i);
  __syncthreads();

  // ---- synthesis L1 + residual + coalesced store
  for (int tr = i; tr < T / 2; tr += 16) {
    float eca = 0.f, ecd = 0.f, oca = 0.f, ocd = 0.f;
#pragma unroll
    for (int m = 0; m < 4; ++m) {
      const float a = sa1[c * C1P + 18 + tr + m];
      const float d = sd1[c * C1P + 18 + tr + m];
      eca = fmaf(LO[2 * m + 1], a, eca);
      ecd = fmaf(HI[2 * m + 1], d, ecd);
      oca = fmaf(LO[2 * m],     a, oca);
      ocd = fmaf(HI[2 * m],     d, ocd);
    }
    const int n = 2 * tr;  // tile-relative
    const float r0 = eca + wd0 * ecd + sx[c * CXP + (n - XLO)];
    const float r1 = oca + wd0 * ocd + sx[c * CXP + (n + 1 - XLO)];
    out[rowbase + (size_t)(n0 + n) * DCH]     = r0;
    out[rowbase + (size_t)(n0 + n + 1) * DCH] = r1;
  }
}

extern "C" void kernel_launch(void* const* d_in, const int* in_sizes, int n_in,
                              void* d_out, int out_size, void* d_ws, size_t ws_size,
                              hipStream_t stream) {
  const float* x  = (const float*)d_in[0];
  const float* wa = (const float*)d_in[1];
  const float* wd = (const float*)d_in[2];
  float* out      = (float*)d_out;

  const int B    = in_sizes[0] / (N0 * DCH);   // 8
  const int grid = B * NDG * NTI;              // 12288, multiple of 8
  wavemix_kernel<<<grid, NT, 0, stream>>>(x, wa, wd, out);
}

// Round 3
// 74.070 us; speedup vs baseline: 3.3383x; 1.7059x over previous
//
#include <hip/hip_runtime.h>

// WaveletMixing: out = x + IDWT3(scale(DWT3(x))) along N per (b,d) channel.
// x: (B=8, N=4096, D=768) f32.
// Block = 8 channels x 256 output samples (+halo). Full pipeline in LDS.
// Global phases: lane = channel-fast (coalesced float4).
// Compute phases: lane = (c2 = tid>>5, i2 = tid&31) + odd LDS strides ->
//   every LDS access pattern is exactly 2 lanes/bank (free on CDNA4).

namespace {

constexpr int NT  = 256;
constexpr int N0  = 4096;
constexpr int DCH = 768;
constexpr int G   = 8;              // channels per block
constexpr int T   = 256;            // output samples per block
constexpr int NTI = N0 / T;         // 16
constexpr int NDG = DCH / G;        // 96

constexpr int L1v = 2051, L2v = 1029, L3v = 518;  // pywt symmetric lengths

// Extended (tile-relative) ranges; stride per channel is ODD (bank freedom).
constexpr int XLO = -42; constexpr int CX = T + 90;    // x: [n0-42, n0+T+47]
constexpr int SX  = 347;
constexpr int A1LO = -18; constexpr int C1 = T / 2 + 42;  // 170
constexpr int S1   = 2 * C1 + 1;    // 341: [a (C1) | d (C1)] per channel
constexpr int A2LO = -6;  constexpr int C2 = T / 4 + 18;  // 82
constexpr int S2   = 2 * C2 + 1;    // 165
constexpr int C3   = T / 8 + 6;     // 38 (A3LO = 0)
constexpr int S3   = 2 * C3 + 1;    // 77
// LDS floats: 8*(347+341+165+77) = 7440 -> 29.8 KB -> 5 blocks/CU.

// db4 analysis filters ascending (pywt); HI[k] = (-1)^(k+1)*LO[7-k].
__device__ constexpr float LO[8] = {
  -0.010597401784997278f,  0.032883011666982945f,  0.030841381835986965f,
  -0.18703481171888114f,  -0.02798376941698385f,   0.6308807679295904f,
   0.7148465705525415f,    0.23037781330885523f };
__device__ constexpr float HI[8] = {
  -0.23037781330885523f,   0.7148465705525415f,   -0.6308807679295904f,
  -0.02798376941698385f,   0.18703481171888114f,   0.030841381835986965f,
  -0.032883011666982945f, -0.010597401784997278f };
// Flipped (ascending-address) copies: F[7-k].
__device__ constexpr float LOF[8] = {
   0.23037781330885523f,   0.7148465705525415f,    0.6308807679295904f,
  -0.02798376941698385f,  -0.18703481171888114f,   0.030841381835986965f,
   0.032883011666982945f, -0.010597401784997278f };
__device__ constexpr float HIF[8] = {
  -0.010597401784997278f, -0.032883011666982945f,  0.030841381835986965f,
   0.18703481171888114f,  -0.02798376941698385f,  -0.6308807679295904f,
   0.7148465705525415f,   -0.23037781330885523f };

__device__ __forceinline__ int refl(int g, int n) {
  g = (g < 0) ? (-g - 1) : g;
  return (g >= n) ? (2 * n - 1 - g) : g;
}

// One analysis level. Output coeff p (storage) = abs index loout_abs+p,
// reflected into [0,lenout). nout == cout. Reads 8 consecutive floats
// (mergeable to ds_read2_b32); writes a/d at dword distance cout (<255,
// mergeable to ds_write2_b32).
__device__ __forceinline__ void analyze(const float* __restrict__ in, int sin_,
                                        int loin_abs, float* __restrict__ outs,
                                        int sout, int cout, int loout_abs,
                                        int lenout, int c, int i) {
  for (int p = i; p < cout; p += 32) {
    const int gp = refl(loout_abs + p, lenout);
    const int qb = 2 * gp + 1 - loin_abs;       // top tap (storage coords)
    const float* __restrict__ s = in + c * sin_ + qb - 7;
    float alo = 0.f, ahi = 0.f;
#pragma unroll
    for (int k = 0; k < 8; ++k) {
      const float v = s[k];
      alo = fmaf(LOF[k], v, alo);
      ahi = fmaf(HIF[k], v, ahi);
    }
    outs[c * sout + p]        = alo;
    outs[c * sout + cout + p] = ahi;
  }
}

// One synthesis level: rec[2t] = sum_m LO[2m+1]*ca[t+m] + HI[2m+1]*cd[t+m];
// rec[2t+1] uses even taps. 8 mergeable reads serve both outputs.
__device__ __forceinline__ void synth(const float* __restrict__ ins, int sin_,
                                      int cin, int pcbase,
                                      float* __restrict__ outs, int sout,
                                      int pobase, float sa, float sd, int ntr,
                                      int c, int i) {
  for (int tr = i; tr < ntr; tr += 32) {
    const float* __restrict__ pa = ins + c * sin_ + pcbase + tr;
    const float* __restrict__ pd = pa + cin;
    float eca = 0.f, ecd = 0.f, oca = 0.f, ocd = 0.f;
#pragma unroll
    for (int m = 0; m < 4; ++m) {
      const float a = pa[m], d = pd[m];
      eca = fmaf(LO[2 * m + 1], a, eca);
      ecd = fmaf(HI[2 * m + 1], d, ecd);
      oca = fmaf(LO[2 * m],     a, oca);
      ocd = fmaf(HI[2 * m],     d, ocd);
    }
    float* __restrict__ o = outs + c * sout + pobase + 2 * tr;
    o[0] = sa * eca + sd * ecd;
    o[1] = sa * oca + sd * ocd;
  }
}

} // namespace

__global__ __launch_bounds__(NT, 5) void wavemix_kernel(
    const float* __restrict__ x, const float* __restrict__ wap,
    const float* __restrict__ wdet, float* __restrict__ out) {
  __shared__ float sx[G * SX];
  __shared__ float s1[G * S1];   // [a1|d1]; a1 later overwritten by r1
  __shared__ float s2[G * S2];   // [a2|d2]; a2 later overwritten by r2
  __shared__ float s3[G * S3];   // [a3|d3]

  // Bijective XCD swizzle; consecutive wg = consecutive n-tiles of one
  // (b,dg) -> halo re-reads and shared 64B lines stay in one XCD's L2.
  const int cpx = gridDim.x >> 3;
  const int wg  = (blockIdx.x & 7) * cpx + (blockIdx.x >> 3);
  const int nt   = wg & (NTI - 1);
  const int rest = wg >> 4;               // / NTI
  const int dg   = rest % NDG;
  const int b    = rest / NDG;
  const int n0   = nt * T;
  const int d0   = dg * G;
  const int tid  = threadIdx.x;

  const size_t base = (size_t)b * N0 * DCH + d0;

  // ---- load extended x tile: float4 of 4 consecutive channels per lane.
  {
    const int q  = tid & 1;               // channel quad
    const int pl = tid >> 1;              // position slot (128)
    for (int p = pl; p < CX; p += 128) {
      const int g = refl(n0 + XLO + p, N0);
      const float4 v =
          *reinterpret_cast<const float4*>(x + base + (size_t)g * DCH + 4 * q);
      float* dst = sx + (4 * q) * SX + p;
      dst[0 * SX] = v.x; dst[1 * SX] = v.y; dst[2 * SX] = v.z; dst[3 * SX] = v.w;
    }
  }

  // compute-phase roles: wave holds channels {2w, 2w+1} -> bank parity mix
  const int c2 = tid >> 5;                // 0..7
  const int i2 = tid & 31;                // 0..31
  const float wa2 = wap[d0 + c2];
  const float wl2 = wdet[2 * DCH + d0 + c2];
  const float wl1 = wdet[1 * DCH + d0 + c2];
  __syncthreads();

  // ---- analysis
  analyze(sx, SX, n0 + XLO,        s1, S1, C1, n0 / 2 + A1LO, L1v, c2, i2);
  __syncthreads();
  analyze(s1, S1, n0 / 2 + A1LO,   s2, S2, C2, n0 / 4 + A2LO, L2v, c2, i2);
  __syncthreads();
  analyze(s2, S2, n0 / 4 + A2LO,   s3, S3, C3, n0 / 8,        L3v, c2, i2);
  __syncthreads();

  // ---- synthesis (weights folded): r2 at a2-part base 6, r1 at a1 base 18
  synth(s3, S3, C3, 0, s2, S2, 6,  wa2, wl2, T / 8 + 2, c2, i2);
  __syncthreads();
  synth(s2, S2, C2, 6, s1, S1, 18, 1.f, wl1, T / 4 + 2, c2, i2);
  __syncthreads();

  // ---- final synthesis + residual + coalesced store (channel-fast roles)
  {
    const int c = tid & 7;
    const int j = tid >> 3;               // 0..31
    const float wl0 = wdet[0 * DCH + d0 + c];
    for (int tr = j; tr < T / 2; tr += 32) {
      const float* __restrict__ pa = s1 + c * S1 + 18 + tr;
      const float* __restrict__ pd = pa + C1;
      float eca = 0.f, ecd = 0.f, oca = 0.f, ocd = 0.f;
#pragma unroll
      for (int m = 0; m < 4; ++m) {
        const float a = pa[m], d = pd[m];
        eca = fmaf(LO[2 * m + 1], a, eca);
        ecd = fmaf(HI[2 * m + 1], d, ecd);
        oca = fmaf(LO[2 * m],     a, oca);
        ocd = fmaf(HI[2 * m],     d, ocd);
      }
      const int n = 2 * tr;
      const float* __restrict__ px = sx + c * SX + (n - XLO);
      out[base + (size_t)(n0 + n) * DCH + c]     = px[0] + (eca + wl0 * ecd);
      out[base + (size_t)(n0 + n + 1) * DCH + c] = px[1] + (oca + wl0 * ocd);
    }
  }
}

extern "C" void kernel_launch(void* const* d_in, const int* in_sizes, int n_in,
                              void* d_out, int out_size, void* d_ws, size_t ws_size,
                              hipStream_t stream) {
  const float* x  = (const float*)d_in[0];
  const float* wa = (const float*)d_in[1];
  const float* wd = (const float*)d_in[2];
  float* out      = (float*)d_out;

  const int B    = in_sizes[0] / (N0 * DCH);   // 8
  const int grid = B * NDG * NTI;              // 12288, multiple of 8
  wavemix_kernel<<<grid, NT, 0, stream>>>(x, wa, wd, out);
}